// Round 24
// baseline (144.383 us; speedup 1.0000x reference)
//
#include <hip/hip_runtime.h>
#include <math.h>

#define TT  2048
#define NH  8
#define DH  128
#define LNT 7.6246189861593985f   // ln(2048)

typedef unsigned short ushort_t;
typedef __bf16 bf16x8 __attribute__((ext_vector_type(8)));
typedef _Float16 f16x8 __attribute__((ext_vector_type(8)));
typedef float f32x4 __attribute__((ext_vector_type(4)));
typedef unsigned int uintx4 __attribute__((ext_vector_type(4)));

#define MFMA16(a, b, c)  __builtin_amdgcn_mfma_f32_16x16x32_bf16(a, b, c, 0, 0, 0)
#define MFMA16F(a, b, c) __builtin_amdgcn_mfma_f32_16x16x32_f16(a, b, c, 0, 0, 0)

#define GLL(gp, lp) __builtin_amdgcn_global_load_lds(                        \
    (const __attribute__((address_space(1))) void*)(gp),                     \
    (__attribute__((address_space(3))) void*)(lp), 16, 0, 0)

__device__ __forceinline__ bf16x8 ld8(const ushort_t* p) {
  uintx4 v = *(const uintx4*)p;
  return __builtin_bit_cast(bf16x8, v);
}
__device__ __forceinline__ f16x8 ld8f(const ushort_t* p) {
  uintx4 v = *(const uintx4*)p;
  return __builtin_bit_cast(f16x8, v);
}
__device__ __forceinline__ ushort_t f2bf(float x) {
  unsigned u = __float_as_uint(x);
  return (ushort_t)((u + 0x7fffu + ((u >> 16) & 1u)) >> 16);
}
__device__ __forceinline__ float bf2f(ushort_t b) {
  return __uint_as_float(((unsigned)b) << 16);
}
__device__ __forceinline__ ushort_t f2h(float x) {
  return __builtin_bit_cast(ushort_t, (_Float16)x);
}
__device__ __forceinline__ float h2f(ushort_t b) {
  return (float)__builtin_bit_cast(_Float16, b);
}

// Fragment layout for [T][T] matrices at the attention MFMA:
//   off(t,s) = ((t>>4)*(T/16) + (s>>4))*256 + ((t>>2)&3)*64 + (s&15)*4 + (t&3)

// ---- workspace layout (float offsets). ws_size = 256 MiB.
enum : size_t {
  F_XF   = 0u,          // x fp16 [1M]
  F_UF   = 1048576u,    // U fp16 [1M]
  F_QF   = 2097152u,    // Q fp16 -> ysh fp16 [8][2048][192] after phase2
  F_KF   = 3145728u,    // K fp16
  F_VBF  = 4194304u,    // V bf16
  F_VT   = 5242880u,    // V'^T bf16 [H*DH, T]
  F_YCF  = 6291456u,    // ycat fp16 (late); stats partials (early)
  F_WCAT = 7340032u,    // Wq|Wk|Wv fp16 [3072,1024]
  F_WOF  = 9437184u,    // Wout fp16 [0.5M]
  F_DIVS = 9961472u,
  F_LST  = 9979904u,
  F_ENTR = 9996288u,
  F_ENT  = 10012672u,
  F_DEP  = 10029056u,
  F_W2F  = 10307584u,   // W2 fp16 padded [128][192]
  F_APH  = 10485760u,   // AP fp16 frag [T,T]
  F_C    = 12582912u,   // C bf16 frag [T,T]
  F_LP   = 6291456u,    // stats partials [8][16384] x3
  F_SAP  = 6422528u,
  F_SCP  = 6553600u,
  F_E    = 16777216u,   // E fp16 frag [H][128][128][256]
  F_YPALL= 33554432u,   // 8 fp16 partial-y buffers x 1,048,576 float-slots
  F_YSH  = 2097152u,
};

__device__ __forceinline__ float blockReduceSum256(float v) {
  __shared__ float sh[4];
  #pragma unroll
  for (int m = 1; m < 64; m <<= 1) v += __shfl_xor(v, m, 64);
  if ((threadIdx.x & 63) == 0) sh[threadIdx.x >> 6] = v;
  __syncthreads();
  float r = sh[0] + sh[1] + sh[2] + sh[3];
  __syncthreads();
  return r;
}

// Fused preprocessing: [0,4192) weight fp16 conversions + W2 pad;
// [4192,6240) rownorm single-pass (x read ONCE; emits Uf AND xf);
// [6240,6248) divsum init.
__global__ __launch_bounds__(256) void k_pre(
    const float* __restrict__ x, const float* __restrict__ Wq,
    const float* __restrict__ Wk, const float* __restrict__ Wv,
    const float* __restrict__ Wo, const float* __restrict__ W2,
    ushort_t* __restrict__ xf, ushort_t* __restrict__ Wcat,
    ushort_t* __restrict__ Wof, ushort_t* __restrict__ W2f,
    ushort_t* __restrict__ Uf, float* __restrict__ divsum) {
  int b = blockIdx.x;
  if (b < 4192) {
    int i = b * 256 + threadIdx.x;
    if (i < 1048576) {
      const float* src; ushort_t* dst; int j;
      if (i < 262144)       { src = Wq; dst = Wcat;           j = i; }
      else if (i < 524288)  { src = Wk; dst = Wcat + 1048576; j = i - 262144; }
      else if (i < 786432)  { src = Wv; dst = Wcat + 2097152; j = i - 524288; }
      else                  { src = Wo; dst = Wof;            j = i - 786432; }
      float4 v = ((const float4*)src)[j];
      uint2 w;
      w.x = (unsigned)f2h(v.x) | ((unsigned)f2h(v.y) << 16);
      w.y = (unsigned)f2h(v.z) | ((unsigned)f2h(v.w) << 16);
      ((uint2*)dst)[j] = w;
    } else {
      int idx = i - 1048576;                    // 0..24575
      int o = idx / 192, c = idx % 192;
      W2f[idx] = (c < 130) ? f2h(W2[o * 130 + c]) : (ushort_t)0;
    }
  } else if (b < 6240) {
    int t = b - 4192;
    float4 v = ((const float4*)(x + (size_t)t * 1024))[threadIdx.x];
    float ss = v.x * v.x + v.y * v.y + v.z * v.z + v.w * v.w;
    ss = blockReduceSum256(ss);
    float inv = 1.f / fmaxf(sqrtf(ss), 1e-12f);
    uint2 wU, wX;
    wU.x = (unsigned)f2h(v.x * inv) | ((unsigned)f2h(v.y * inv) << 16);
    wU.y = (unsigned)f2h(v.z * inv) | ((unsigned)f2h(v.w * inv) << 16);
    wX.x = (unsigned)f2h(v.x) | ((unsigned)f2h(v.y) << 16);
    wX.y = (unsigned)f2h(v.z) | ((unsigned)f2h(v.w) << 16);
    ((uint2*)(Uf + (size_t)t * 1024))[threadIdx.x] = wU;
    ((uint2*)(xf + (size_t)t * 1024))[threadIdx.x] = wX;
  } else {
    int idx = (b - 6240) * 256 + threadIdx.x;
    if (idx < TT) divsum[idx] = (float)TT;
  }
}

// ---- m97-style NT GEMM tile body: 128x128 tile, BK=64, single-buffered.
// MODE: 7 symmetric-C bf16 frag (+mirror, row+col divsum atomics).
template <int MODE>
__device__ __forceinline__ void gemm_tile(
    ushort_t* As, ushort_t* Bs,
    const ushort_t* A, const ushort_t* B,
    float* Df, ushort_t* Dh,
    int M, int N, int K, int m0, int n0) {
  int tid = threadIdx.x, lane = tid & 63, w = tid >> 6;
  int l15 = lane & 15, lg = lane >> 4;
  int wr = w >> 1, wc = w & 1;

  const ushort_t* ga[4];
  const ushort_t* gb[4];
  ushort_t* la[4];
  ushort_t* lb[4];
  #pragma unroll
  for (int j = 0; j < 4; j++) {
    int u = (4 * w + j) * 64 + lane;
    int row = u >> 3;
    int kc8 = (u & 7) ^ (row & 7);
    ga[j] = A + (size_t)(m0 + row) * K + kc8 * 8;
    gb[j] = B + (size_t)(n0 + row) * K + kc8 * 8;
    la[j] = As + (4 * w + j) * 512;
    lb[j] = Bs + (4 * w + j) * 512;
  }

  f32x4 acc[4][4];
  #pragma unroll
  for (int i = 0; i < 4; i++)
    #pragma unroll
    for (int ct = 0; ct < 4; ct++) acc[i][ct] = (f32x4)0.f;

  for (int k0 = 0; k0 < K; k0 += 64) {
    __syncthreads();
    #pragma unroll
    for (int j = 0; j < 4; j++) {
      GLL(ga[j] + k0, la[j]);
      GLL(gb[j] + k0, lb[j]);
    }
    __syncthreads();
    #pragma unroll
    for (int kc = 0; kc < 2; kc++) {
      f16x8 af[4], bfr[4];
      #pragma unroll
      for (int i = 0; i < 4; i++) {
        int ra = wr * 64 + i * 16 + l15;
        af[i] = ld8f(As + (ra * 8 + ((kc * 4 + lg) ^ (ra & 7))) * 8);
        int rb = wc * 64 + i * 16 + l15;
        bfr[i] = ld8f(Bs + (rb * 8 + ((kc * 4 + lg) ^ (rb & 7))) * 8);
      }
      #pragma unroll
      for (int i = 0; i < 4; i++)
        #pragma unroll
        for (int ct = 0; ct < 4; ct++)
          acc[i][ct] = MFMA16F(af[i], bfr[ct], acc[i][ct]);
    }
  }
  if (MODE == 7) {
    #pragma unroll
    for (int i = 0; i < 4; i++) {
      float rs[4] = {0.f, 0.f, 0.f, 0.f};
      #pragma unroll
      for (int ct = 0; ct < 4; ct++) {
        size_t tile_t = (size_t)(m0 + wr * 64 + i * 16) >> 4;
        size_t tile_s = (size_t)(n0 + wc * 64 + ct * 16) >> 4;
        uint2 wv;
        wv.x = (unsigned)f2bf(acc[i][ct][0]) | ((unsigned)f2bf(acc[i][ct][1]) << 16);
        wv.y = (unsigned)f2bf(acc[i][ct][2]) | ((unsigned)f2bf(acc[i][ct][3]) << 16);
        *(uint2*)(Dh + (tile_t * (size_t)(N >> 4) + tile_s) * 256 + lg * 64 + l15 * 4) = wv;
        rs[0] += acc[i][ct][0]; rs[1] += acc[i][ct][1];
        rs[2] += acc[i][ct][2]; rs[3] += acc[i][ct][3];
      }
      #pragma unroll
      for (int r = 0; r < 4; r++) {
        float s = rs[r];
        s += __shfl_xor(s, 1, 64); s += __shfl_xor(s, 2, 64);
        s += __shfl_xor(s, 4, 64); s += __shfl_xor(s, 8, 64);
        if (l15 == 0)
          atomicAdd(&Df[m0 + wr * 64 + i * 16 + lg * 4 + r], -s);
      }
    }
    if (m0 != n0) {
      #pragma unroll
      for (int ct = 0; ct < 4; ct++) {
        float cs = 0.f;
        #pragma unroll
        for (int i = 0; i < 4; i++)
          #pragma unroll
          for (int r = 0; r < 4; r++) cs += acc[i][ct][r];
        cs += __shfl_xor(cs, 16, 64);
        cs += __shfl_xor(cs, 32, 64);
        if (lane < 16)
          atomicAdd(&Df[n0 + wc * 64 + ct * 16 + l15], -cs);
      }
      #pragma unroll
      for (int i = 0; i < 4; i++) {
        #pragma unroll
        for (int ct = 0; ct < 4; ct++) {
          size_t mbase = (((size_t)(n0 + wc * 64 + ct * 16) >> 4) * (size_t)(N >> 4)
                          + ((size_t)(m0 + wr * 64 + i * 16) >> 4)) * 256;
          #pragma unroll
          for (int r = 0; r < 4; r++)
            Dh[mbase + (l15 >> 2) * 64 + (lg * 4 + r) * 4 + (l15 & 3)] =
                f2bf(acc[i][ct][r]);
        }
      }
    }
  }
}

// 64-row GEMM tile, 2-phase double-buffered (proven R22).
// MODE: 0 f32 out; 3 QKV split; 4 ys remap.
template <int MODE>
__device__ __forceinline__ void gemm64(
    ushort_t* As0, ushort_t* As1, ushort_t* Bs0, ushort_t* Bs1,
    const ushort_t* A, const ushort_t* B,
    float* Df, ushort_t* Dh,
    ushort_t* Dq, ushort_t* Dk, ushort_t* Dv,
    int N, int K, int m0, int n0) {
  int tid = threadIdx.x, lane = tid & 63, w = tid >> 6;
  int l15 = lane & 15, lg = lane >> 4;
  int wc = w;                                  // wave owns cols wc*32..wc*32+31

  const ushort_t* gaA[2];
  int laOff[2];
  #pragma unroll
  for (int j = 0; j < 2; j++) {
    int u = (2 * w + j) * 64 + lane;           // 0..511 A units
    int row = u >> 3;
    int kc8 = (u & 7) ^ (row & 7);
    gaA[j] = A + (size_t)(m0 + row) * K + kc8 * 8;
    laOff[j] = (2 * w + j) * 512;
  }
  const ushort_t* gb[4];
  int lbOff[4];
  #pragma unroll
  for (int j = 0; j < 4; j++) {
    int u = (4 * w + j) * 64 + lane;           // 0..1023 B units
    int row = u >> 3;
    int kc8 = (u & 7) ^ (row & 7);
    gb[j] = B + (size_t)(n0 + row) * K + kc8 * 8;
    lbOff[j] = (4 * w + j) * 512;
  }

  f32x4 acc[4][2];
  #pragma unroll
  for (int i = 0; i < 4; i++)
    #pragma unroll
    for (int ct = 0; ct < 2; ct++) acc[i][ct] = (f32x4)0.f;

  // prologue: stage k=0 into buf0
  #pragma unroll
  for (int j = 0; j < 2; j++) GLL(gaA[j], As0 + laOff[j]);
  #pragma unroll
  for (int j = 0; j < 4; j++) GLL(gb[j], Bs0 + lbOff[j]);
  __syncthreads();                             // drains prologue loads

  int cur = 0;
  for (int k0 = 0; k0 < K; k0 += 64) {
    ushort_t* Ac = cur ? As1 : As0;
    ushort_t* Bc = cur ? Bs1 : Bs0;
    int k1 = k0 + 64;
    if (k1 < K) {                              // stage NEXT tile before compute
      ushort_t* An = cur ? As0 : As1;
      ushort_t* Bn = cur ? Bs0 : Bs1;
      #pragma unroll
      for (int j = 0; j < 2; j++) GLL(gaA[j] + k1, An + laOff[j]);
      #pragma unroll
      for (int j = 0; j < 4; j++) GLL(gb[j] + k1, Bn + lbOff[j]);
    }
    #pragma unroll
    for (int kc = 0; kc < 2; kc++) {
      f16x8 af[4], bfr[2];
      #pragma unroll
      for (int i = 0; i < 4; i++) {
        int ra = i * 16 + l15;
        af[i] = ld8f(Ac + (ra * 8 + ((kc * 4 + lg) ^ (ra & 7))) * 8);
      }
      #pragma unroll
      for (int ct = 0; ct < 2; ct++) {
        int rb = wc * 32 + ct * 16 + l15;
        bfr[ct] = ld8f(Bc + (rb * 8 + ((kc * 4 + lg) ^ (rb & 7))) * 8);
      }
      #pragma unroll
      for (int i = 0; i < 4; i++)
        #pragma unroll
        for (int ct = 0; ct < 2; ct++)
          acc[i][ct] = MFMA16F(af[i], bfr[ct], acc[i][ct]);
    }
    __syncthreads();                           // next loads landed + all reads done
    cur ^= 1;
  }
  #pragma unroll
  for (int i = 0; i < 4; i++) {
    #pragma unroll
    for (int ct = 0; ct < 2; ct++) {
      #pragma unroll
      for (int r = 0; r < 4; r++) {
        size_t mm = m0 + i * 16 + lg * 4 + r;
        size_t nn = n0 + wc * 32 + ct * 16 + l15;
        float v = acc[i][ct][r];
        if (MODE == 0) Df[mm * N + nn] = v;
        if (MODE == 3) {
          if (nn < 1024) Dq[mm * 1024 + nn] = f2h(v);
          else if (nn < 2048) Dk[mm * 1024 + nn - 1024] = f2h(v);
          else Dv[mm * 1024 + nn - 2048] = f2bf(v);
        }
        if (MODE == 4) {
          size_t hh = mm >> 11, tt2 = mm & 2047;
          Dh[tt2 * 1024 + hh * 128 + nn] = f2h(v);
        }
      }
    }
  }
}

template <int MODE>
__global__ __launch_bounds__(256) void k_gemm64(
    const ushort_t* __restrict__ A, const ushort_t* __restrict__ B,
    float* __restrict__ Df, ushort_t* __restrict__ Dh,
    int N, int K) {
  __shared__ __align__(16) ushort_t SA[2][64 * 64];
  __shared__ __align__(16) ushort_t SB[2][128 * 64];
  gemm64<MODE>(SA[0], SA[1], SB[0], SB[1], A, B, Df, Dh,
               nullptr, nullptr, nullptr,
               N, K, blockIdx.y * 64, blockIdx.x * 128);
}

// Fused: symmetric C (0..135) + QKV64 2-phase (136..903) + AP table (904..2951).
__global__ __launch_bounds__(256) void k_cqkv(
    const ushort_t* __restrict__ Uf, const ushort_t* __restrict__ xf,
    const ushort_t* __restrict__ Wcat,
    ushort_t* __restrict__ Cf, ushort_t* __restrict__ Qf,
    ushort_t* __restrict__ Kf, ushort_t* __restrict__ Vbf,
    float* __restrict__ divsum, ushort_t* __restrict__ APf) {
  __shared__ __align__(16) ushort_t SA[2][64 * 64];
  __shared__ __align__(16) ushort_t SB[2][128 * 64];
  int bid = blockIdx.x;
  if (bid < 136) {
    int rem = bid, bt = 0;
    while (rem >= 16 - bt) { rem -= 16 - bt; ++bt; }
    int bs = bt + rem;                         // bt <= bs
    gemm_tile<7>(&SA[0][0], &SB[0][0], Uf, Uf, divsum, Cf,
                 TT, TT, 1024, bt * 128, bs * 128);
  } else if (bid < 904) {
    int b = bid - 136;
    gemm64<3>(SA[0], SA[1], SB[0], SB[1], xf, Wcat, nullptr, nullptr,
              Qf, Kf, Vbf, 3072, 1024, (b / 24) * 64, (b % 24) * 128);
  } else {
    int bb = bid - 904;
    int tile_t = bb >> 4, sub = bb & 15;
    int base = sub * 2048;
    for (int u0 = threadIdx.x; u0 < 2048; u0 += 256) {
      int u = base + u0;
      int tile_s = u >> 8, slot = u & 255;
      int lg = slot >> 6, l15 = (slot >> 2) & 15, r = slot & 3;
      int t = tile_t * 16 + lg * 4 + r;
      int s = tile_s * 16 + l15;
      int i = s >> 1;
      float invf = __expf((float)i * -0.017988946039016016f); // -ln(1e4)/512
      float ang = (float)t * invf;
      APf[(size_t)tile_t * 32768 + u] = f2h((s & 1) ? __cosf(ang) : __sinf(ang));
    }
  }
}

// ---- phase 1: fp16 QK^T (AP as MFMA C-init), fixed-max stats (M=0),
//      frag C loads, K LDS double-buffered (one barrier/iter), z=8,
//      stores E fp16 frags ----
__global__ __launch_bounds__(512, 4) void k_phase1m(
    const ushort_t* __restrict__ Qf, const ushort_t* __restrict__ Kf,
    const ushort_t* __restrict__ APf, const ushort_t* __restrict__ Cf,
    ushort_t* __restrict__ Ef,
    float* __restrict__ Lp, float* __restrict__ sap, float* __restrict__ scp) {
  int h = blockIdx.y, z = blockIdx.z;
  int tid = threadIdx.x, lane = tid & 63, w = tid >> 6;
  int l15 = lane & 15, lg = lane >> 4;
  int rowbase = blockIdx.x * 128 + w * 16;
  int s_begin = z * 256, s_end = s_begin + 256;
  __shared__ __align__(16) ushort_t Ks[2][64 * 128];   // fp16, unit-swizzled, dbuf

  f16x8 q[4];
  {
    const ushort_t* qp = Qf + (size_t)(rowbase + l15) * 1024 + h * DH + lg * 8;
    #pragma unroll
    for (int kc = 0; kc < 4; kc++) q[kc] = ld8f(qp + kc * 32);
  }
  const ushort_t* apb = APf + (size_t)(rowbase >> 4) * 32768 + lane * 4;
  const ushort_t* cfb = Cf  + (size_t)(rowbase >> 4) * 32768 + lane * 4;
  ushort_t* eb = Ef + ((size_t)(h * 128 + (rowbase >> 4)) * 128) * 256 + lane * 4;

  int n0 = w * 128 + lane;
  int sr0 = n0 >> 4, su0 = n0 & 15, sr1 = sr0 + 4;
  int wo0 = sr0 * 128 + ((su0 ^ (sr0 & 7)) * 8);
  int wo1 = sr1 * 128 + ((su0 ^ (sr1 & 7)) * 8);
  const ushort_t* kg0 = Kf + (size_t)sr0 * 1024 + h * DH + su0 * 8;
  const ushort_t* kg1 = Kf + (size_t)sr1 * 1024 + h * DH + su0 * 8;

  float Lv[4], sae[4], snc[4];
  #pragma unroll
  for (int r = 0; r < 4; r++) { Lv[r] = 0.f; sae[r] = 0.f; snc[r] = 0.f; }

  // prologue: stage s_begin into Ks[0]
  uintx4 ka = *(const uintx4*)(kg0 + (size_t)s_begin * 1024);
  uintx4 kb = *(const uintx4*)(kg1 + (size_t)s_begin * 1024);
  *(uintx4*)(Ks[0] + wo0) = ka;
  *(uintx4*)(Ks[0] + wo1) = kb;
  __syncthreads();
  if (s_begin + 64 < s_end) {
    ka = *(const uintx4*)(kg0 + (size_t)(s_begin + 64) * 1024);
    kb = *(const uintx4*)(kg1 + (size_t)(s_begin + 64) * 1024);
  }

  int cur = 0;
  for (int s0 = s_begin; s0 < s_end; s0 += 64) {
    int ts0 = s0 >> 4;
    f32x4 acc[4];
    float cc[4][4];
    #pragma unroll
    for (int ct = 0; ct < 4; ct++) {
      uint2 ap2 = *(const uint2*)(apb + (size_t)(ts0 + ct) * 256);
      uint2 c2  = *(const uint2*)(cfb + (size_t)(ts0 + ct) * 256);
      acc[ct][0] = h2f((ushort_t)(ap2.x & 0xffffu));
      acc[ct][1] = h2f((ushort_t)(ap2.x >> 16));
      acc[ct][2] = h2f((ushort_t)(ap2.y & 0xffffu));
      acc[ct][3] = h2f((ushort_t)(ap2.y >> 16));
      cc[ct][0] = bf2f((ushort_t)(c2.x & 0xffffu));
      cc[ct][1] = bf2f((ushort_t)(c2.x >> 16));
      cc[ct][2] = bf2f((ushort_t)(c2.y & 0xffffu));
      cc[ct][3] = bf2f((ushort_t)(c2.y >> 16));
    }
    int s1 = s0 + 64;
    if (s1 < s_end) {                          // write NEXT K tile into other buf
      *(uintx4*)(Ks[cur ^ 1] + wo0) = ka;
      *(uintx4*)(Ks[cur ^ 1] + wo1) = kb;
      int s2 = s0 + 128;
      if (s2 < s_end) {
        ka = *(const uintx4*)(kg0 + (size_t)s2 * 1024);
        kb = *(const uintx4*)(kg1 + (size_t)s2 * 1024);
      }
    }
    const ushort_t* Kc = Ks[cur];
    #pragma unroll
    for (int ct = 0; ct < 4; ct++) {
      int row = ct * 16 + l15, rb = row * 128, rsw = row & 7;
      #pragma unroll
      for (int kc = 0; kc < 4; kc++) {
        f16x8 b = ld8f(Kc + rb + (((kc * 4 + lg) ^ rsw) * 8));
        acc[ct] = MFMA16F(q[kc], b, acc[ct]);
      }
    }
    #pragma unroll
    for (int ct = 0; ct < 4; ct++) {       // store E fp16 frags for phase 2
      uint2 ev;
      ev.x = (unsigned)f2h(acc[ct][0]) | ((unsigned)f2h(acc[ct][1]) << 16);
      ev.y = (unsigned)f2h(acc[ct][2]) | ((unsigned)f2h(acc[ct][3]) << 16);
      *(uint2*)(eb + (size_t)(ts0 + ct) * 256) = ev;
    }
    #pragma unroll
    for (int r = 0; r < 4; r++) {          // fixed-max stats (M=0)
      float e0 = acc[0][r], e1 = acc[1][r], e2 = acc[2][r], e3 = acc[3][r];
      float p0 = __expf(e0), p1 = __expf(e1), p2 = __expf(e2), p3 = __expf(e3);
      Lv[r]  += (p0 + p1) + (p2 + p3);
      sae[r] += (p0 * e0 + p1 * e1) + (p2 * e2 + p3 * e3);
      snc[r] += (p0 * cc[0][r] + p1 * cc[1][r]) + (p2 * cc[2][r] + p3 * cc[3][r]);
    }
    __syncthreads();                       // all reads of Ks[cur] done; writes visible
    cur ^= 1;
  }
  #pragma unroll
  for (int r = 0; r < 4; r++) {
    #pragma unroll
    for (int m = 1; m < 16; m <<= 1) {
      Lv[r]  += __shfl_xor(Lv[r], m, 64);
      sae[r] += __shfl_xor(sae[r], m, 64);
      snc[r] += __shfl_xor(snc[r], m, 64);
    }
  }
  if (l15 == 0) {
    #pragma unroll
    for (int r = 0; r < 4; r++) {
      int t = rowbase + lg * 4 + r;
      size_t idx = (size_t)z * (NH * TT) + h * TT + t;
      Lp[idx] = Lv[r]; sap[idx] = sae[r]; scp[idx] = snc[r];
    }
  }
}

__global__ __launch_bounds__(256) void k_combine(
    const float* __restrict__ Lp, const float* __restrict__ sap,
    const float* __restrict__ scp, const float* __restrict__ divsum,
    float* __restrict__ Lst, float* __restrict__ entraw, float* __restrict__ dep) {
  int i = blockIdx.x * 256 + threadIdx.x;
  if (i >= NH * TT) return;
  float L = 0.f, sa = 0.f, sc = 0.f;
  #pragma unroll
  for (int c = 0; c < 8; c++) {
    size_t idx = (size_t)c * (NH * TT) + i;
    L += Lp[idx]; sa += sap[idx]; sc += scp[idx];
  }
  float logL = __logf(L);
  Lst[i] = logL;
  entraw[i] = (logL - sa / L) * (1.0f / LNT);
  int t = i & (TT - 1);
  dep[i] = (1.f - sc / L) / divsum[t];
}

// Fused: entnorm (blocks 0..7) + vprime (blocks 8..263).
__global__ __launch_bounds__(256) void k_entvp(
    const float* __restrict__ entraw, float* __restrict__ ent,
    const ushort_t* __restrict__ Vbf, const float* __restrict__ dep,
    ushort_t* __restrict__ VT) {
  __shared__ float tile[64][130];
  int b = blockIdx.x;
  if (b < 8) {
    int h = b;
    float s = 0.f;
    for (int t = threadIdx.x; t < TT; t += 256) s += fabsf(entraw[h * TT + t]);
    s = blockReduceSum256(s);
    float inv = 1.f / fmaxf(s, 1e-12f);
    for (int t = threadIdx.x; t < TT; t += 256)
      ent[h * TT + t] = entraw[h * TT + t] * inv;
  } else {
    int bb = b - 8;
    int h = bb >> 5, s0 = (bb & 31) * 64;
    int tid = threadIdx.x;
    for (int idx = tid; idx < 64 * 64; idx += 256) {
      int r = idx >> 6, c2 = (idx & 63) * 2;
      unsigned u = *(const unsigned*)&Vbf[(size_t)(s0 + r) * 1024 + h * DH + c2];
      tile[r][c2] = bf2f((ushort_t)(u & 0xffffu));
      tile[r][c2 + 1] = bf2f((ushort_t)(u >> 16));
    }
    __syncthreads();
    int e = tid >> 1, sh = (tid & 1) * 32;
    #pragma unroll
    for (int g = 0; g < 8; g++) {
      int sb = sh + g * 4;
      float v0 = tile[sb + 0][e] * (1.f + dep[h * TT + s0 + sb + 0]);
      float v1 = tile[sb + 1][e] * (1.f + dep[h * TT + s0 + sb + 1]);
      float v2 = tile[sb + 2][e] * (1.f + dep[h * TT + s0 + sb + 2]);
      float v3 = tile[sb + 3][e] * (1.f + dep[h * TT + s0 + sb + 3]);
      uint2 wv;
      wv.x = (unsigned)f2bf(v0) | ((unsigned)f2bf(v1) << 16);
      wv.y = (unsigned)f2bf(v2) | ((unsigned)f2bf(v3) << 16);
      *(uint2*)&VT[(size_t)(h * DH + e) * TT + s0 + sb] = wv;
    }
  }
}

// ---- phase 2: reads E frags, exp(e - logL), V' LDS double-buffered
//      (one barrier/iter), z=8 ----
__global__ __launch_bounds__(512) void k_phase2m(
    const ushort_t* __restrict__ Ef, const ushort_t* __restrict__ VT,
    const float* __restrict__ Lst, const float* __restrict__ dep,
    ushort_t* __restrict__ ypall, float* __restrict__ out2) {
  int h = (blockIdx.y + 7) & 7;   // h=7 (the out2 head) dispatches first
  int z = blockIdx.z;
  int tid = threadIdx.x, lane = tid & 63, w = tid >> 6;
  int l15 = lane & 15, lg = lane >> 4;
  int rowbase = blockIdx.x * 128 + w * 16;
  bool last = (h == NH - 1);
  int s_begin = z * 256, s_end = s_begin + 256;
  ushort_t* yp = ypall + (size_t)z * 2097152;

  __shared__ __align__(16) ushort_t Vs[2][128 * 64]; // bf16 V' tile [e][s], dbuf
  __shared__ __align__(16) ushort_t Pst[8][16][72];  // bf16 P, per wave

  float ml[4];
  #pragma unroll
  for (int r = 0; r < 4; r++) ml[r] = Lst[h * TT + rowbase + lg * 4 + r];
  const ushort_t* eb = Ef + ((size_t)(h * 128 + (rowbase >> 4)) * 128) * 256 + lane * 4;

  int n0 = w * 128 + lane;
  int ve0 = n0 >> 3, vu0 = n0 & 7;
  int vwo0 = ve0 * 64 + ((vu0 ^ (ve0 & 7)) * 8);
  int vwo1 = vwo0 + 512;
  const ushort_t* vg0 = VT + (size_t)(h * DH + ve0) * TT + vu0 * 8;
  const ushort_t* vg1 = vg0 + (size_t)8 * TT;

  f32x4 yacc[8];
  #pragma unroll
  for (int et = 0; et < 8; et++) yacc[et] = (f32x4)0.f;

  // prologue: stage s_begin into Vs[0]
  uintx4 va = *(const uintx4*)(vg0 + s_begin);
  uintx4 vb = *(const uintx4*)(vg1 + s_begin);
  *(uintx4*)(Vs[0] + vwo0) = va;
  *(uintx4*)(Vs[0] + vwo1) = vb;
  __syncthreads();
  if (s_begin + 64 < s_end) {
    va = *(const uintx4*)(vg0 + s_begin + 64);
    vb = *(const uintx4*)(vg1 + s_begin + 64);
  }

  int cur = 0;
  for (int s0 = s_begin; s0 < s_end; s0 += 64) {
    int ts0 = s0 >> 4;
    uint2 e2[4];
    #pragma unroll
    for (int ct = 0; ct < 4; ct++)
      e2[ct] = *(const uint2*)(eb + (size_t)(ts0 + ct) * 256);
    int s1 = s0 + 64;
    if (s1 < s_end) {                          // write NEXT V tile into other buf
      *(uintx4*)(Vs[cur ^ 1] + vwo0) = va;
      *(uintx4*)(Vs[cur ^ 1] + vwo1) = vb;
      int s2 = s0 + 128;
      if (s2 < s_end) {
        va = *(const uintx4*)(vg0 + s2);
        vb = *(const uintx4*)(vg1 + s2);
      }
    }
    float dv[4];
    if (last) {
      #pragma unroll
      for (int ct = 0; ct < 4; ct++) dv[ct] = dep[(NH - 1) * TT + s0 + ct * 16 + l15];
    }
    #pragma unroll
    for (int ct = 0; ct < 4; ct++) {
      float e0 = h2f((ushort_t)(e2[ct].x & 0xffffu));
      float e1 = h2f((ushort_t)(e2[ct].x >> 16));
      float e3 = h2f((ushort_t)(e2[ct].y & 0xffffu));
      float e4 = h2f((ushort_t)(e2[ct].y >> 16));
      float a0 = __expf(e0 - ml[0]);
      float a1 = __expf(e1 - ml[1]);
      float a2 = __expf(e3 - ml[2]);
      float a3 = __expf(e4 - ml[3]);
      Pst[w][lg * 4 + 0][ct * 16 + l15] = f2bf(a0);
      Pst[w][lg * 4 + 1][ct * 16 + l15] = f2bf(a1);
      Pst[w][lg * 4 + 2][ct * 16 + l15] = f2bf(a2);
      Pst[w][lg * 4 + 3][ct * 16 + l15] = f2bf(a3);
      if (last) {
        float sc = 1.f + dv[ct];
        out2[(size_t)(rowbase + lg * 4 + 0) * TT + s0 + ct * 16 + l15] = a0 * sc;
        out2[(size_t)(rowbase + lg * 4 + 1) * TT + s0 + ct * 16 + l15] = a1 * sc;
        out2[(size_t)(rowbase + lg * 4 + 2) * TT + s0 + ct * 16 + l15] = a2 * sc;
        out2[(size_t)(rowbase + lg * 4 + 3) * TT + s0 + ct * 16 + l15] = a3 * sc;
      }
    }
    asm volatile("" ::: "memory");   // wave-internal: P writes before P reads
    const ushort_t* Vc = Vs[cur];
    #pragma unroll
    for (int c = 0; c < 2; c++) {
      bf16x8 ap = *(const bf16x8*)&Pst[w][l15][c * 32 + lg * 8];
      #pragma unroll
      for (int et = 0; et < 8; et++) {
        int e = et * 16 + l15;
        bf16x8 bv = ld8(Vc + e * 64 + (((c * 4 + lg) ^ (l15 & 7)) * 8));
        yacc[et] = MFMA16(ap, bv, yacc[et]);
      }
    }
    __syncthreads();                 // all reads of Vs[cur] done; next writes visible
    cur ^= 1;
  }
  #pragma unroll
  for (int et = 0; et < 8; et++)
    #pragma unroll
    for (int r = 0; r < 4; r++)
      yp[((size_t)h * TT + rowbase + lg * 4 + r) * DH + et * 16 + l15] = f2h(yacc[et][r]);
}

// ysh[h][t][0:128] = fp16(sum yp0..7); [128]=ent, [129]=dep, [130:192]=0
__device__ __forceinline__ void acc8(const ushort_t* p, float* s) {
  uintx4 v = *(const uintx4*)p;
  #pragma unroll
  for (int q = 0; q < 4; q++) {
    s[q * 2]     += h2f((ushort_t)(v[q] & 0xffffu));
    s[q * 2 + 1] += h2f((ushort_t)(v[q] >> 16));
  }
}
__global__ __launch_bounds__(256) void k_ysum(
    const ushort_t* __restrict__ ypall,
    const float* __restrict__ ent, const float* __restrict__ dep,
    ushort_t* __restrict__ ysh) {
  int i = blockIdx.x * 256 + threadIdx.x;     // [0, 8*2048*16)
  int g = i & 15, t = (i >> 4) & 2047, h = i >> 15;
  size_t src = ((size_t)h * TT + t) * DH + g * 8;
  float s[8];
  #pragma unroll
  for (int q = 0; q < 8; q++) s[q] = 0.f;
  #pragma unroll
  for (int b = 0; b < 8; b++) acc8(ypall + (size_t)b * 2097152 + src, s);
  uintx4 o;
  o[0] = (unsigned)f2h(s[0]) | ((unsigned)f2h(s[1]) << 16);
  o[1] = (unsigned)f2h(s[2]) | ((unsigned)f2h(s[3]) << 16);
  o[2] = (unsigned)f2h(s[4]) | ((unsigned)f2h(s[5]) << 16);
  o[3] = (unsigned)f2h(s[6]) | ((unsigned)f2h(s[7]) << 16);
  ushort_t* row = ysh + ((size_t)h * TT + t) * 192;
  *(uintx4*)(row + g * 8) = o;
  if (g == 0) {
    uint2 cz;
    cz.x = (unsigned)f2h(ent[h * TT + t]) | ((unsigned)f2h(dep[h * TT + t]) << 16);
    cz.y = 0u;
    *(uint2*)(row + 128) = cz;
    uint2 z2; z2.x = 0u; z2.y = 0u;
    #pragma unroll
    for (int q = 132; q < 192; q += 4) *(uint2*)(row + q) = z2;
  }
}

extern "C" void kernel_launch(void* const* d_in, const int* in_sizes, int n_in,
                              void* d_out, int out_size, void* d_ws, size_t ws_size,
                              hipStream_t stream) {
  const float* x  = (const float*)d_in[0];
  const float* Wq = (const float*)d_in[1];
  const float* Wk = (const float*)d_in[2];
  const float* Wv = (const float*)d_in[3];
  const float* W2 = (const float*)d_in[4];
  const float* Wo = (const float*)d_in[5];
  float* out  = (float*)d_out;                  // [T,1024]
  float* out2 = out + (size_t)TT * 1024;        // att_win[-1] [T,T]
  float* ws = (float*)d_ws;

  ushort_t* xf   = (ushort_t*)(ws + F_XF);
  ushort_t* Uf   = (ushort_t*)(ws + F_UF);
  ushort_t* Qf   = (ushort_t*)(ws + F_QF);
  ushort_t* Kf   = (ushort_t*)(ws + F_KF);
  ushort_t* Vbf  = (ushort_t*)(ws + F_VBF);
  ushort_t* VT   = (ushort_t*)(ws + F_VT);
  ushort_t* ycf  = (ushort_t*)(ws + F_YCF);
  ushort_t* Wcat = (ushort_t*)(ws + F_WCAT);
  ushort_t* Wof  = (ushort_t*)(ws + F_WOF);
  ushort_t* W2f  = (ushort_t*)(ws + F_W2F);
  ushort_t* APf  = (ushort_t*)(ws + F_APH);
  ushort_t* ysh  = (ushort_t*)(ws + F_YSH);
  ushort_t* Cf   = (ushort_t*)(ws + F_C);
  ushort_t* Ef   = (ushort_t*)(ws + F_E);
  ushort_t* ypall= (ushort_t*)(ws + F_YPALL);
  float* divsum = ws + F_DIVS;
  float* Lst    = ws + F_LST;
  float* entraw = ws + F_ENTR;
  float* ent    = ws + F_ENT;
  float* dep    = ws + F_DEP;
  float* Lp     = ws + F_LP;
  float* sap    = ws + F_SAP;
  float* scp    = ws + F_SCP;

  k_pre<<<6248, 256, 0, stream>>>(x, Wq, Wk, Wv, Wo, W2,
                                  xf, Wcat, Wof, W2f, Uf, divsum);
  k_cqkv<<<2952, 256, 0, stream>>>(Uf, xf, Wcat, Cf, Qf, Kf, Vbf, divsum, APf);

  k_phase1m<<<dim3(16, NH, 8), 512, 0, stream>>>(Qf, Kf, APf, Cf, Ef, Lp, sap, scp);
  k_combine<<<64, 256, 0, stream>>>(Lp, sap, scp, divsum, Lst, entraw, dep);
  k_entvp<<<264, 256, 0, stream>>>(entraw, ent, Vbf, dep, VT);
  k_phase2m<<<dim3(16, NH, 8), 512, 0, stream>>>(Ef, VT, Lst, dep, ypall, out2);
  k_ysum<<<1024, 256, 0, stream>>>(ypall, ent, dep, ysh);
  k_gemm64<4><<<dim3(1, 256), 256, 0, stream>>>(ysh, W2f, nullptr, ycf, 128, 192);
  k_gemm64<0><<<dim3(8, 32), 256, 0, stream>>>(ycf, Wof, out, nullptr, 1024, 1024);
}

// Round 25
// 142.607 us; speedup vs baseline: 1.0125x; 1.0125x over previous
//
#include <hip/hip_runtime.h>
#include <math.h>

#define TT  2048
#define NH  8
#define DH  128
#define LNT 7.6246189861593985f   // ln(2048)

typedef unsigned short ushort_t;
typedef __bf16 bf16x8 __attribute__((ext_vector_type(8)));
typedef _Float16 f16x8 __attribute__((ext_vector_type(8)));
typedef float f32x4 __attribute__((ext_vector_type(4)));
typedef unsigned int uintx4 __attribute__((ext_vector_type(4)));

#define MFMA16(a, b, c)  __builtin_amdgcn_mfma_f32_16x16x32_bf16(a, b, c, 0, 0, 0)
#define MFMA16F(a, b, c) __builtin_amdgcn_mfma_f32_16x16x32_f16(a, b, c, 0, 0, 0)

#define GLL(gp, lp) __builtin_amdgcn_global_load_lds(                        \
    (const __attribute__((address_space(1))) void*)(gp),                     \
    (__attribute__((address_space(3))) void*)(lp), 16, 0, 0)

__device__ __forceinline__ bf16x8 ld8(const ushort_t* p) {
  uintx4 v = *(const uintx4*)p;
  return __builtin_bit_cast(bf16x8, v);
}
__device__ __forceinline__ f16x8 ld8f(const ushort_t* p) {
  uintx4 v = *(const uintx4*)p;
  return __builtin_bit_cast(f16x8, v);
}
__device__ __forceinline__ ushort_t f2bf(float x) {
  unsigned u = __float_as_uint(x);
  return (ushort_t)((u + 0x7fffu + ((u >> 16) & 1u)) >> 16);
}
__device__ __forceinline__ float bf2f(ushort_t b) {
  return __uint_as_float(((unsigned)b) << 16);
}
__device__ __forceinline__ ushort_t f2h(float x) {
  return __builtin_bit_cast(ushort_t, (_Float16)x);
}
__device__ __forceinline__ float h2f(ushort_t b) {
  return (float)__builtin_bit_cast(_Float16, b);
}

// Fragment layout for [T][T] matrices at the attention MFMA:
//   off(t,s) = ((t>>4)*(T/16) + (s>>4))*256 + ((t>>2)&3)*64 + (s&15)*4 + (t&3)

// ---- workspace layout (float offsets). ws_size = 256 MiB.
enum : size_t {
  F_XF   = 0u,          // x fp16 [1M]
  F_UF   = 1048576u,    // U fp16 [1M]
  F_QF   = 2097152u,    // Q fp16 -> ysh fp16 [8][2048][192] after phase2
  F_KF   = 3145728u,    // K fp16
  F_VBF  = 4194304u,    // V bf16
  F_VT   = 5242880u,    // V'^T bf16 [H*DH, T]
  F_YCF  = 6291456u,    // ycat fp16 (late); stats partials (early)
  F_WCAT = 7340032u,    // Wq|Wk|Wv fp16 [3072,1024]
  F_WOF  = 9437184u,    // Wout fp16 [0.5M]
  F_DIVS = 9961472u,
  F_LST  = 9979904u,
  F_ENTR = 9996288u,
  F_ENT  = 10012672u,
  F_DEP  = 10029056u,
  F_W2F  = 10307584u,   // W2 fp16 padded [128][192]
  F_APH  = 10485760u,   // AP fp16 frag [T,T]
  F_C    = 12582912u,   // C bf16 frag [T,T]
  F_LP   = 6291456u,    // stats partials [8][16384] x3
  F_SAP  = 6422528u,
  F_SCP  = 6553600u,
  F_E    = 16777216u,   // E fp16 frag [H][128][128][256]
  F_YPALL= 33554432u,   // 8 fp16 partial-y buffers x 1,048,576 float-slots
  F_YSH  = 2097152u,
};

__device__ __forceinline__ float blockReduceSum256(float v) {
  __shared__ float sh[4];
  #pragma unroll
  for (int m = 1; m < 64; m <<= 1) v += __shfl_xor(v, m, 64);
  if ((threadIdx.x & 63) == 0) sh[threadIdx.x >> 6] = v;
  __syncthreads();
  float r = sh[0] + sh[1] + sh[2] + sh[3];
  __syncthreads();
  return r;
}

// Fused preprocessing: [0,4192) weight fp16 conversions + W2 pad;
// [4192,6240) rownorm single-pass (x read ONCE; emits Uf AND xf);
// [6240,6248) divsum init.
__global__ __launch_bounds__(256) void k_pre(
    const float* __restrict__ x, const float* __restrict__ Wq,
    const float* __restrict__ Wk, const float* __restrict__ Wv,
    const float* __restrict__ Wo, const float* __restrict__ W2,
    ushort_t* __restrict__ xf, ushort_t* __restrict__ Wcat,
    ushort_t* __restrict__ Wof, ushort_t* __restrict__ W2f,
    ushort_t* __restrict__ Uf, float* __restrict__ divsum) {
  int b = blockIdx.x;
  if (b < 4192) {
    int i = b * 256 + threadIdx.x;
    if (i < 1048576) {
      const float* src; ushort_t* dst; int j;
      if (i < 262144)       { src = Wq; dst = Wcat;           j = i; }
      else if (i < 524288)  { src = Wk; dst = Wcat + 1048576; j = i - 262144; }
      else if (i < 786432)  { src = Wv; dst = Wcat + 2097152; j = i - 524288; }
      else                  { src = Wo; dst = Wof;            j = i - 786432; }
      float4 v = ((const float4*)src)[j];
      uint2 w;
      w.x = (unsigned)f2h(v.x) | ((unsigned)f2h(v.y) << 16);
      w.y = (unsigned)f2h(v.z) | ((unsigned)f2h(v.w) << 16);
      ((uint2*)dst)[j] = w;
    } else {
      int idx = i - 1048576;                    // 0..24575
      int o = idx / 192, c = idx % 192;
      W2f[idx] = (c < 130) ? f2h(W2[o * 130 + c]) : (ushort_t)0;
    }
  } else if (b < 6240) {
    int t = b - 4192;
    float4 v = ((const float4*)(x + (size_t)t * 1024))[threadIdx.x];
    float ss = v.x * v.x + v.y * v.y + v.z * v.z + v.w * v.w;
    ss = blockReduceSum256(ss);
    float inv = 1.f / fmaxf(sqrtf(ss), 1e-12f);
    uint2 wU, wX;
    wU.x = (unsigned)f2h(v.x * inv) | ((unsigned)f2h(v.y * inv) << 16);
    wU.y = (unsigned)f2h(v.z * inv) | ((unsigned)f2h(v.w * inv) << 16);
    wX.x = (unsigned)f2h(v.x) | ((unsigned)f2h(v.y) << 16);
    wX.y = (unsigned)f2h(v.z) | ((unsigned)f2h(v.w) << 16);
    ((uint2*)(Uf + (size_t)t * 1024))[threadIdx.x] = wU;
    ((uint2*)(xf + (size_t)t * 1024))[threadIdx.x] = wX;
  } else {
    int idx = (b - 6240) * 256 + threadIdx.x;
    if (idx < TT) divsum[idx] = (float)TT;
  }
}

// ---- m97-style NT GEMM tile body: 128x128 tile, BK=64, single-buffered.
// MODE: 7 symmetric-C bf16 frag (+mirror, row+col divsum atomics).
template <int MODE>
__device__ __forceinline__ void gemm_tile(
    ushort_t* As, ushort_t* Bs,
    const ushort_t* A, const ushort_t* B,
    float* Df, ushort_t* Dh,
    int M, int N, int K, int m0, int n0) {
  int tid = threadIdx.x, lane = tid & 63, w = tid >> 6;
  int l15 = lane & 15, lg = lane >> 4;
  int wr = w >> 1, wc = w & 1;

  const ushort_t* ga[4];
  const ushort_t* gb[4];
  ushort_t* la[4];
  ushort_t* lb[4];
  #pragma unroll
  for (int j = 0; j < 4; j++) {
    int u = (4 * w + j) * 64 + lane;
    int row = u >> 3;
    int kc8 = (u & 7) ^ (row & 7);
    ga[j] = A + (size_t)(m0 + row) * K + kc8 * 8;
    gb[j] = B + (size_t)(n0 + row) * K + kc8 * 8;
    la[j] = As + (4 * w + j) * 512;
    lb[j] = Bs + (4 * w + j) * 512;
  }

  f32x4 acc[4][4];
  #pragma unroll
  for (int i = 0; i < 4; i++)
    #pragma unroll
    for (int ct = 0; ct < 4; ct++) acc[i][ct] = (f32x4)0.f;

  for (int k0 = 0; k0 < K; k0 += 64) {
    __syncthreads();
    #pragma unroll
    for (int j = 0; j < 4; j++) {
      GLL(ga[j] + k0, la[j]);
      GLL(gb[j] + k0, lb[j]);
    }
    __syncthreads();
    #pragma unroll
    for (int kc = 0; kc < 2; kc++) {
      f16x8 af[4], bfr[4];
      #pragma unroll
      for (int i = 0; i < 4; i++) {
        int ra = wr * 64 + i * 16 + l15;
        af[i] = ld8f(As + (ra * 8 + ((kc * 4 + lg) ^ (ra & 7))) * 8);
        int rb = wc * 64 + i * 16 + l15;
        bfr[i] = ld8f(Bs + (rb * 8 + ((kc * 4 + lg) ^ (rb & 7))) * 8);
      }
      #pragma unroll
      for (int i = 0; i < 4; i++)
        #pragma unroll
        for (int ct = 0; ct < 4; ct++)
          acc[i][ct] = MFMA16F(af[i], bfr[ct], acc[i][ct]);
    }
  }
  if (MODE == 7) {
    #pragma unroll
    for (int i = 0; i < 4; i++) {
      float rs[4] = {0.f, 0.f, 0.f, 0.f};
      #pragma unroll
      for (int ct = 0; ct < 4; ct++) {
        size_t tile_t = (size_t)(m0 + wr * 64 + i * 16) >> 4;
        size_t tile_s = (size_t)(n0 + wc * 64 + ct * 16) >> 4;
        uint2 wv;
        wv.x = (unsigned)f2bf(acc[i][ct][0]) | ((unsigned)f2bf(acc[i][ct][1]) << 16);
        wv.y = (unsigned)f2bf(acc[i][ct][2]) | ((unsigned)f2bf(acc[i][ct][3]) << 16);
        *(uint2*)(Dh + (tile_t * (size_t)(N >> 4) + tile_s) * 256 + lg * 64 + l15 * 4) = wv;
        rs[0] += acc[i][ct][0]; rs[1] += acc[i][ct][1];
        rs[2] += acc[i][ct][2]; rs[3] += acc[i][ct][3];
      }
      #pragma unroll
      for (int r = 0; r < 4; r++) {
        float s = rs[r];
        s += __shfl_xor(s, 1, 64); s += __shfl_xor(s, 2, 64);
        s += __shfl_xor(s, 4, 64); s += __shfl_xor(s, 8, 64);
        if (l15 == 0)
          atomicAdd(&Df[m0 + wr * 64 + i * 16 + lg * 4 + r], -s);
      }
    }
    if (m0 != n0) {
      #pragma unroll
      for (int ct = 0; ct < 4; ct++) {
        float cs = 0.f;
        #pragma unroll
        for (int i = 0; i < 4; i++)
          #pragma unroll
          for (int r = 0; r < 4; r++) cs += acc[i][ct][r];
        cs += __shfl_xor(cs, 16, 64);
        cs += __shfl_xor(cs, 32, 64);
        if (lane < 16)
          atomicAdd(&Df[n0 + wc * 64 + ct * 16 + l15], -cs);
      }
      #pragma unroll
      for (int i = 0; i < 4; i++) {
        #pragma unroll
        for (int ct = 0; ct < 4; ct++) {
          size_t mbase = (((size_t)(n0 + wc * 64 + ct * 16) >> 4) * (size_t)(N >> 4)
                          + ((size_t)(m0 + wr * 64 + i * 16) >> 4)) * 256;
          #pragma unroll
          for (int r = 0; r < 4; r++)
            Dh[mbase + (l15 >> 2) * 64 + (lg * 4 + r) * 4 + (l15 & 3)] =
                f2bf(acc[i][ct][r]);
        }
      }
    }
  }
}

// 64-row GEMM tile, 2-phase double-buffered (proven R22).
// MODE: 0 f32 out; 3 QKV split; 4 ys remap.
template <int MODE>
__device__ __forceinline__ void gemm64(
    ushort_t* As0, ushort_t* As1, ushort_t* Bs0, ushort_t* Bs1,
    const ushort_t* A, const ushort_t* B,
    float* Df, ushort_t* Dh,
    ushort_t* Dq, ushort_t* Dk, ushort_t* Dv,
    int N, int K, int m0, int n0) {
  int tid = threadIdx.x, lane = tid & 63, w = tid >> 6;
  int l15 = lane & 15, lg = lane >> 4;
  int wc = w;                                  // wave owns cols wc*32..wc*32+31

  const ushort_t* gaA[2];
  int laOff[2];
  #pragma unroll
  for (int j = 0; j < 2; j++) {
    int u = (2 * w + j) * 64 + lane;           // 0..511 A units
    int row = u >> 3;
    int kc8 = (u & 7) ^ (row & 7);
    gaA[j] = A + (size_t)(m0 + row) * K + kc8 * 8;
    laOff[j] = (2 * w + j) * 512;
  }
  const ushort_t* gb[4];
  int lbOff[4];
  #pragma unroll
  for (int j = 0; j < 4; j++) {
    int u = (4 * w + j) * 64 + lane;           // 0..1023 B units
    int row = u >> 3;
    int kc8 = (u & 7) ^ (row & 7);
    gb[j] = B + (size_t)(n0 + row) * K + kc8 * 8;
    lbOff[j] = (4 * w + j) * 512;
  }

  f32x4 acc[4][2];
  #pragma unroll
  for (int i = 0; i < 4; i++)
    #pragma unroll
    for (int ct = 0; ct < 2; ct++) acc[i][ct] = (f32x4)0.f;

  // prologue: stage k=0 into buf0
  #pragma unroll
  for (int j = 0; j < 2; j++) GLL(gaA[j], As0 + laOff[j]);
  #pragma unroll
  for (int j = 0; j < 4; j++) GLL(gb[j], Bs0 + lbOff[j]);
  __syncthreads();                             // drains prologue loads

  int cur = 0;
  for (int k0 = 0; k0 < K; k0 += 64) {
    ushort_t* Ac = cur ? As1 : As0;
    ushort_t* Bc = cur ? Bs1 : Bs0;
    int k1 = k0 + 64;
    if (k1 < K) {                              // stage NEXT tile before compute
      ushort_t* An = cur ? As0 : As1;
      ushort_t* Bn = cur ? Bs0 : Bs1;
      #pragma unroll
      for (int j = 0; j < 2; j++) GLL(gaA[j] + k1, An + laOff[j]);
      #pragma unroll
      for (int j = 0; j < 4; j++) GLL(gb[j] + k1, Bn + lbOff[j]);
    }
    #pragma unroll
    for (int kc = 0; kc < 2; kc++) {
      f16x8 af[4], bfr[2];
      #pragma unroll
      for (int i = 0; i < 4; i++) {
        int ra = i * 16 + l15;
        af[i] = ld8f(Ac + (ra * 8 + ((kc * 4 + lg) ^ (ra & 7))) * 8);
      }
      #pragma unroll
      for (int ct = 0; ct < 2; ct++) {
        int rb = wc * 32 + ct * 16 + l15;
        bfr[ct] = ld8f(Bc + (rb * 8 + ((kc * 4 + lg) ^ (rb & 7))) * 8);
      }
      #pragma unroll
      for (int i = 0; i < 4; i++)
        #pragma unroll
        for (int ct = 0; ct < 2; ct++)
          acc[i][ct] = MFMA16F(af[i], bfr[ct], acc[i][ct]);
    }
    __syncthreads();                           // next loads landed + all reads done
    cur ^= 1;
  }
  #pragma unroll
  for (int i = 0; i < 4; i++) {
    #pragma unroll
    for (int ct = 0; ct < 2; ct++) {
      #pragma unroll
      for (int r = 0; r < 4; r++) {
        size_t mm = m0 + i * 16 + lg * 4 + r;
        size_t nn = n0 + wc * 32 + ct * 16 + l15;
        float v = acc[i][ct][r];
        if (MODE == 0) Df[mm * N + nn] = v;
        if (MODE == 3) {
          if (nn < 1024) Dq[mm * 1024 + nn] = f2h(v);
          else if (nn < 2048) Dk[mm * 1024 + nn - 1024] = f2h(v);
          else Dv[mm * 1024 + nn - 2048] = f2bf(v);
        }
        if (MODE == 4) {
          size_t hh = mm >> 11, tt2 = mm & 2047;
          Dh[tt2 * 1024 + hh * 128 + nn] = f2h(v);
        }
      }
    }
  }
}

template <int MODE>
__global__ __launch_bounds__(256) void k_gemm64(
    const ushort_t* __restrict__ A, const ushort_t* __restrict__ B,
    float* __restrict__ Df, ushort_t* __restrict__ Dh,
    int N, int K) {
  __shared__ __align__(16) ushort_t SA[2][64 * 64];
  __shared__ __align__(16) ushort_t SB[2][128 * 64];
  gemm64<MODE>(SA[0], SA[1], SB[0], SB[1], A, B, Df, Dh,
               nullptr, nullptr, nullptr,
               N, K, blockIdx.y * 64, blockIdx.x * 128);
}

// Fused: symmetric C (0..135) + QKV64 2-phase (136..903) + AP table (904..2951).
__global__ __launch_bounds__(256) void k_cqkv(
    const ushort_t* __restrict__ Uf, const ushort_t* __restrict__ xf,
    const ushort_t* __restrict__ Wcat,
    ushort_t* __restrict__ Cf, ushort_t* __restrict__ Qf,
    ushort_t* __restrict__ Kf, ushort_t* __restrict__ Vbf,
    float* __restrict__ divsum, ushort_t* __restrict__ APf) {
  __shared__ __align__(16) ushort_t SA[2][64 * 64];
  __shared__ __align__(16) ushort_t SB[2][128 * 64];
  int bid = blockIdx.x;
  if (bid < 136) {
    int rem = bid, bt = 0;
    while (rem >= 16 - bt) { rem -= 16 - bt; ++bt; }
    int bs = bt + rem;                         // bt <= bs
    gemm_tile<7>(&SA[0][0], &SB[0][0], Uf, Uf, divsum, Cf,
                 TT, TT, 1024, bt * 128, bs * 128);
  } else if (bid < 904) {
    int b = bid - 136;
    gemm64<3>(SA[0], SA[1], SB[0], SB[1], xf, Wcat, nullptr, nullptr,
              Qf, Kf, Vbf, 3072, 1024, (b / 24) * 64, (b % 24) * 128);
  } else {
    int bb = bid - 904;
    int tile_t = bb >> 4, sub = bb & 15;
    int base = sub * 2048;
    for (int u0 = threadIdx.x; u0 < 2048; u0 += 256) {
      int u = base + u0;
      int tile_s = u >> 8, slot = u & 255;
      int lg = slot >> 6, l15 = (slot >> 2) & 15, r = slot & 3;
      int t = tile_t * 16 + lg * 4 + r;
      int s = tile_s * 16 + l15;
      int i = s >> 1;
      float invf = __expf((float)i * -0.017988946039016016f); // -ln(1e4)/512
      float ang = (float)t * invf;
      APf[(size_t)tile_t * 32768 + u] = f2h((s & 1) ? __cosf(ang) : __sinf(ang));
    }
  }
}

// ---- phase 1: fp16 QK^T (AP as MFMA C-init), fixed-max stats (M=0),
//      frag C loads, K LDS double-buffered (one barrier/iter), z=8,
//      stores E fp16 frags ----
__global__ __launch_bounds__(512, 4) void k_phase1m(
    const ushort_t* __restrict__ Qf, const ushort_t* __restrict__ Kf,
    const ushort_t* __restrict__ APf, const ushort_t* __restrict__ Cf,
    ushort_t* __restrict__ Ef,
    float* __restrict__ Lp, float* __restrict__ sap, float* __restrict__ scp) {
  int h = blockIdx.y, z = blockIdx.z;
  int tid = threadIdx.x, lane = tid & 63, w = tid >> 6;
  int l15 = lane & 15, lg = lane >> 4;
  int rowbase = blockIdx.x * 128 + w * 16;
  int s_begin = z * 256, s_end = s_begin + 256;
  __shared__ __align__(16) ushort_t Ks[2][64 * 128];   // fp16, unit-swizzled, dbuf

  f16x8 q[4];
  {
    const ushort_t* qp = Qf + (size_t)(rowbase + l15) * 1024 + h * DH + lg * 8;
    #pragma unroll
    for (int kc = 0; kc < 4; kc++) q[kc] = ld8f(qp + kc * 32);
  }
  const ushort_t* apb = APf + (size_t)(rowbase >> 4) * 32768 + lane * 4;
  const ushort_t* cfb = Cf  + (size_t)(rowbase >> 4) * 32768 + lane * 4;
  ushort_t* eb = Ef + ((size_t)(h * 128 + (rowbase >> 4)) * 128) * 256 + lane * 4;

  int n0 = w * 128 + lane;
  int sr0 = n0 >> 4, su0 = n0 & 15, sr1 = sr0 + 4;
  int wo0 = sr0 * 128 + ((su0 ^ (sr0 & 7)) * 8);
  int wo1 = sr1 * 128 + ((su0 ^ (sr1 & 7)) * 8);
  const ushort_t* kg0 = Kf + (size_t)sr0 * 1024 + h * DH + su0 * 8;
  const ushort_t* kg1 = Kf + (size_t)sr1 * 1024 + h * DH + su0 * 8;

  float Lv[4], sae[4], snc[4];
  #pragma unroll
  for (int r = 0; r < 4; r++) { Lv[r] = 0.f; sae[r] = 0.f; snc[r] = 0.f; }

  // prologue: stage s_begin into Ks[0]
  uintx4 ka = *(const uintx4*)(kg0 + (size_t)s_begin * 1024);
  uintx4 kb = *(const uintx4*)(kg1 + (size_t)s_begin * 1024);
  *(uintx4*)(Ks[0] + wo0) = ka;
  *(uintx4*)(Ks[0] + wo1) = kb;
  __syncthreads();
  if (s_begin + 64 < s_end) {
    ka = *(const uintx4*)(kg0 + (size_t)(s_begin + 64) * 1024);
    kb = *(const uintx4*)(kg1 + (size_t)(s_begin + 64) * 1024);
  }

  int cur = 0;
  for (int s0 = s_begin; s0 < s_end; s0 += 64) {
    int ts0 = s0 >> 4;
    f32x4 acc[4];
    float cc[4][4];
    #pragma unroll
    for (int ct = 0; ct < 4; ct++) {
      uint2 ap2 = *(const uint2*)(apb + (size_t)(ts0 + ct) * 256);
      uint2 c2  = *(const uint2*)(cfb + (size_t)(ts0 + ct) * 256);
      acc[ct][0] = h2f((ushort_t)(ap2.x & 0xffffu));
      acc[ct][1] = h2f((ushort_t)(ap2.x >> 16));
      acc[ct][2] = h2f((ushort_t)(ap2.y & 0xffffu));
      acc[ct][3] = h2f((ushort_t)(ap2.y >> 16));
      cc[ct][0] = bf2f((ushort_t)(c2.x & 0xffffu));
      cc[ct][1] = bf2f((ushort_t)(c2.x >> 16));
      cc[ct][2] = bf2f((ushort_t)(c2.y & 0xffffu));
      cc[ct][3] = bf2f((ushort_t)(c2.y >> 16));
    }
    int s1 = s0 + 64;
    if (s1 < s_end) {                          // write NEXT K tile into other buf
      *(uintx4*)(Ks[cur ^ 1] + wo0) = ka;
      *(uintx4*)(Ks[cur ^ 1] + wo1) = kb;
      int s2 = s0 + 128;
      if (s2 < s_end) {
        ka = *(const uintx4*)(kg0 + (size_t)s2 * 1024);
        kb = *(const uintx4*)(kg1 + (size_t)s2 * 1024);
      }
    }
    const ushort_t* Kc = Ks[cur];
    #pragma unroll
    for (int ct = 0; ct < 4; ct++) {
      int row = ct * 16 + l15, rb = row * 128, rsw = row & 7;
      #pragma unroll
      for (int kc = 0; kc < 4; kc++) {
        f16x8 b = ld8f(Kc + rb + (((kc * 4 + lg) ^ rsw) * 8));
        acc[ct] = MFMA16F(q[kc], b, acc[ct]);
      }
    }
    #pragma unroll
    for (int ct = 0; ct < 4; ct++) {       // store E fp16 frags for phase 2
      uint2 ev;
      ev.x = (unsigned)f2h(acc[ct][0]) | ((unsigned)f2h(acc[ct][1]) << 16);
      ev.y = (unsigned)f2h(acc[ct][2]) | ((unsigned)f2h(acc[ct][3]) << 16);
      *(uint2*)(eb + (size_t)(ts0 + ct) * 256) = ev;
    }
    #pragma unroll
    for (int r = 0; r < 4; r++) {          // fixed-max stats (M=0)
      float e0 = acc[0][r], e1 = acc[1][r], e2 = acc[2][r], e3 = acc[3][r];
      float p0 = __expf(e0), p1 = __expf(e1), p2 = __expf(e2), p3 = __expf(e3);
      Lv[r]  += (p0 + p1) + (p2 + p3);
      sae[r] += (p0 * e0 + p1 * e1) + (p2 * e2 + p3 * e3);
      snc[r] += (p0 * cc[0][r] + p1 * cc[1][r]) + (p2 * cc[2][r] + p3 * cc[3][r]);
    }
    __syncthreads();                       // all reads of Ks[cur] done; writes visible
    cur ^= 1;
  }
  #pragma unroll
  for (int r = 0; r < 4; r++) {
    #pragma unroll
    for (int m = 1; m < 16; m <<= 1) {
      Lv[r]  += __shfl_xor(Lv[r], m, 64);
      sae[r] += __shfl_xor(sae[r], m, 64);
      snc[r] += __shfl_xor(snc[r], m, 64);
    }
  }
  if (l15 == 0) {
    #pragma unroll
    for (int r = 0; r < 4; r++) {
      int t = rowbase + lg * 4 + r;
      size_t idx = (size_t)z * (NH * TT) + h * TT + t;
      Lp[idx] = Lv[r]; sap[idx] = sae[r]; scp[idx] = snc[r];
    }
  }
}

__global__ __launch_bounds__(256) void k_combine(
    const float* __restrict__ Lp, const float* __restrict__ sap,
    const float* __restrict__ scp, const float* __restrict__ divsum,
    float* __restrict__ Lst, float* __restrict__ entraw, float* __restrict__ dep) {
  int i = blockIdx.x * 256 + threadIdx.x;
  if (i >= NH * TT) return;
  float L = 0.f, sa = 0.f, sc = 0.f;
  #pragma unroll
  for (int c = 0; c < 8; c++) {
    size_t idx = (size_t)c * (NH * TT) + i;
    L += Lp[idx]; sa += sap[idx]; sc += scp[idx];
  }
  float logL = __logf(L);
  Lst[i] = logL;
  entraw[i] = (logL - sa / L) * (1.0f / LNT);
  int t = i & (TT - 1);
  dep[i] = (1.f - sc / L) / divsum[t];
}

// Fused: entnorm (blocks 0..7) + vprime (blocks 8..263).
__global__ __launch_bounds__(256) void k_entvp(
    const float* __restrict__ entraw, float* __restrict__ ent,
    const ushort_t* __restrict__ Vbf, const float* __restrict__ dep,
    ushort_t* __restrict__ VT) {
  __shared__ float tile[64][130];
  int b = blockIdx.x;
  if (b < 8) {
    int h = b;
    float s = 0.f;
    for (int t = threadIdx.x; t < TT; t += 256) s += fabsf(entraw[h * TT + t]);
    s = blockReduceSum256(s);
    float inv = 1.f / fmaxf(s, 1e-12f);
    for (int t = threadIdx.x; t < TT; t += 256)
      ent[h * TT + t] = entraw[h * TT + t] * inv;
  } else {
    int bb = b - 8;
    int h = bb >> 5, s0 = (bb & 31) * 64;
    int tid = threadIdx.x;
    for (int idx = tid; idx < 64 * 64; idx += 256) {
      int r = idx >> 6, c2 = (idx & 63) * 2;
      unsigned u = *(const unsigned*)&Vbf[(size_t)(s0 + r) * 1024 + h * DH + c2];
      tile[r][c2] = bf2f((ushort_t)(u & 0xffffu));
      tile[r][c2 + 1] = bf2f((ushort_t)(u >> 16));
    }
    __syncthreads();
    int e = tid >> 1, sh = (tid & 1) * 32;
    #pragma unroll
    for (int g = 0; g < 8; g++) {
      int sb = sh + g * 4;
      float v0 = tile[sb + 0][e] * (1.f + dep[h * TT + s0 + sb + 0]);
      float v1 = tile[sb + 1][e] * (1.f + dep[h * TT + s0 + sb + 1]);
      float v2 = tile[sb + 2][e] * (1.f + dep[h * TT + s0 + sb + 2]);
      float v3 = tile[sb + 3][e] * (1.f + dep[h * TT + s0 + sb + 3]);
      uint2 wv;
      wv.x = (unsigned)f2bf(v0) | ((unsigned)f2bf(v1) << 16);
      wv.y = (unsigned)f2bf(v2) | ((unsigned)f2bf(v3) << 16);
      *(uint2*)&VT[(size_t)(h * DH + e) * TT + s0 + sb] = wv;
    }
  }
}

// ---- phase 2: reads E frags, exp(e - logL), LDS-staged V', z=8 ----
__global__ __launch_bounds__(512, 4) void k_phase2m(
    const ushort_t* __restrict__ Ef, const ushort_t* __restrict__ VT,
    const float* __restrict__ Lst, const float* __restrict__ dep,
    ushort_t* __restrict__ ypall, float* __restrict__ out2) {
  int h = (blockIdx.y + 7) & 7;   // h=7 (the out2 head) dispatches first
  int z = blockIdx.z;
  int tid = threadIdx.x, lane = tid & 63, w = tid >> 6;
  int l15 = lane & 15, lg = lane >> 4;
  int rowbase = blockIdx.x * 128 + w * 16;
  bool last = (h == NH - 1);
  int s_begin = z * 256, s_end = s_begin + 256;
  ushort_t* yp = ypall + (size_t)z * 2097152;

  __shared__ __align__(16) ushort_t Vs[128 * 64];   // bf16 V' tile [e][s]
  __shared__ __align__(16) ushort_t Pst[8][16][72]; // bf16 P, per wave

  float ml[4];
  #pragma unroll
  for (int r = 0; r < 4; r++) ml[r] = Lst[h * TT + rowbase + lg * 4 + r];
  const ushort_t* eb = Ef + ((size_t)(h * 128 + (rowbase >> 4)) * 128) * 256 + lane * 4;

  int n0 = w * 128 + lane;
  int ve0 = n0 >> 3, vu0 = n0 & 7;
  int vwo0 = ve0 * 64 + ((vu0 ^ (ve0 & 7)) * 8);
  int vwo1 = vwo0 + 512;
  const ushort_t* vg0 = VT + (size_t)(h * DH + ve0) * TT + vu0 * 8;
  const ushort_t* vg1 = vg0 + (size_t)8 * TT;

  f32x4 yacc[8];
  #pragma unroll
  for (int et = 0; et < 8; et++) yacc[et] = (f32x4)0.f;

  uintx4 va = *(const uintx4*)(vg0 + s_begin);
  uintx4 vb = *(const uintx4*)(vg1 + s_begin);

  for (int s0 = s_begin; s0 < s_end; s0 += 64) {
    int ts0 = s0 >> 4;
    uint2 e2[4];
    #pragma unroll
    for (int ct = 0; ct < 4; ct++)
      e2[ct] = *(const uint2*)(eb + (size_t)(ts0 + ct) * 256);
    __syncthreads();
    *(uintx4*)(Vs + vwo0) = va;
    *(uintx4*)(Vs + vwo1) = vb;
    int s1 = s0 + 64;
    if (s1 < s_end) {
      va = *(const uintx4*)(vg0 + s1);
      vb = *(const uintx4*)(vg1 + s1);
    }
    __syncthreads();
    float dv[4];
    if (last) {
      #pragma unroll
      for (int ct = 0; ct < 4; ct++) dv[ct] = dep[(NH - 1) * TT + s0 + ct * 16 + l15];
    }
    #pragma unroll
    for (int ct = 0; ct < 4; ct++) {
      float e0 = h2f((ushort_t)(e2[ct].x & 0xffffu));
      float e1 = h2f((ushort_t)(e2[ct].x >> 16));
      float e3 = h2f((ushort_t)(e2[ct].y & 0xffffu));
      float e4 = h2f((ushort_t)(e2[ct].y >> 16));
      float a0 = __expf(e0 - ml[0]);
      float a1 = __expf(e1 - ml[1]);
      float a2 = __expf(e3 - ml[2]);
      float a3 = __expf(e4 - ml[3]);
      Pst[w][lg * 4 + 0][ct * 16 + l15] = f2bf(a0);
      Pst[w][lg * 4 + 1][ct * 16 + l15] = f2bf(a1);
      Pst[w][lg * 4 + 2][ct * 16 + l15] = f2bf(a2);
      Pst[w][lg * 4 + 3][ct * 16 + l15] = f2bf(a3);
      if (last) {
        float sc = 1.f + dv[ct];
        out2[(size_t)(rowbase + lg * 4 + 0) * TT + s0 + ct * 16 + l15] = a0 * sc;
        out2[(size_t)(rowbase + lg * 4 + 1) * TT + s0 + ct * 16 + l15] = a1 * sc;
        out2[(size_t)(rowbase + lg * 4 + 2) * TT + s0 + ct * 16 + l15] = a2 * sc;
        out2[(size_t)(rowbase + lg * 4 + 3) * TT + s0 + ct * 16 + l15] = a3 * sc;
      }
    }
    asm volatile("" ::: "memory");   // wave-internal: P writes before P reads
    #pragma unroll
    for (int c = 0; c < 2; c++) {
      bf16x8 ap = *(const bf16x8*)&Pst[w][l15][c * 32 + lg * 8];
      #pragma unroll
      for (int et = 0; et < 8; et++) {
        int e = et * 16 + l15;
        bf16x8 bv = ld8(Vs + e * 64 + (((c * 4 + lg) ^ (l15 & 7)) * 8));
        yacc[et] = MFMA16(ap, bv, yacc[et]);
      }
    }
    asm volatile("" ::: "memory");
  }
  #pragma unroll
  for (int et = 0; et < 8; et++)
    #pragma unroll
    for (int r = 0; r < 4; r++)
      yp[((size_t)h * TT + rowbase + lg * 4 + r) * DH + et * 16 + l15] = f2h(yacc[et][r]);
}

// ysh[h][t][0:128] = fp16(sum yp0..7); [128]=ent, [129]=dep, [130:192]=0
__device__ __forceinline__ void acc8(const ushort_t* p, float* s) {
  uintx4 v = *(const uintx4*)p;
  #pragma unroll
  for (int q = 0; q < 4; q++) {
    s[q * 2]     += h2f((ushort_t)(v[q] & 0xffffu));
    s[q * 2 + 1] += h2f((ushort_t)(v[q] >> 16));
  }
}
__global__ __launch_bounds__(256) void k_ysum(
    const ushort_t* __restrict__ ypall,
    const float* __restrict__ ent, const float* __restrict__ dep,
    ushort_t* __restrict__ ysh) {
  int i = blockIdx.x * 256 + threadIdx.x;     // [0, 8*2048*16)
  int g = i & 15, t = (i >> 4) & 2047, h = i >> 15;
  size_t src = ((size_t)h * TT + t) * DH + g * 8;
  float s[8];
  #pragma unroll
  for (int q = 0; q < 8; q++) s[q] = 0.f;
  #pragma unroll
  for (int b = 0; b < 8; b++) acc8(ypall + (size_t)b * 2097152 + src, s);
  uintx4 o;
  o[0] = (unsigned)f2h(s[0]) | ((unsigned)f2h(s[1]) << 16);
  o[1] = (unsigned)f2h(s[2]) | ((unsigned)f2h(s[3]) << 16);
  o[2] = (unsigned)f2h(s[4]) | ((unsigned)f2h(s[5]) << 16);
  o[3] = (unsigned)f2h(s[6]) | ((unsigned)f2h(s[7]) << 16);
  ushort_t* row = ysh + ((size_t)h * TT + t) * 192;
  *(uintx4*)(row + g * 8) = o;
  if (g == 0) {
    uint2 cz;
    cz.x = (unsigned)f2h(ent[h * TT + t]) | ((unsigned)f2h(dep[h * TT + t]) << 16);
    cz.y = 0u;
    *(uint2*)(row + 128) = cz;
    uint2 z2; z2.x = 0u; z2.y = 0u;
    #pragma unroll
    for (int q = 132; q < 192; q += 4) *(uint2*)(row + q) = z2;
  }
}

extern "C" void kernel_launch(void* const* d_in, const int* in_sizes, int n_in,
                              void* d_out, int out_size, void* d_ws, size_t ws_size,
                              hipStream_t stream) {
  const float* x  = (const float*)d_in[0];
  const float* Wq = (const float*)d_in[1];
  const float* Wk = (const float*)d_in[2];
  const float* Wv = (const float*)d_in[3];
  const float* W2 = (const float*)d_in[4];
  const float* Wo = (const float*)d_in[5];
  float* out  = (float*)d_out;                  // [T,1024]
  float* out2 = out + (size_t)TT * 1024;        // att_win[-1] [T,T]
  float* ws = (float*)d_ws;

  ushort_t* xf   = (ushort_t*)(ws + F_XF);
  ushort_t* Uf   = (ushort_t*)(ws + F_UF);
  ushort_t* Qf   = (ushort_t*)(ws + F_QF);
  ushort_t* Kf   = (ushort_t*)(ws + F_KF);
  ushort_t* Vbf  = (ushort_t*)(ws + F_VBF);
  ushort_t* VT   = (ushort_t*)(ws + F_VT);
  ushort_t* ycf  = (ushort_t*)(ws + F_YCF);
  ushort_t* Wcat = (ushort_t*)(ws + F_WCAT);
  ushort_t* Wof  = (ushort_t*)(ws + F_WOF);
  ushort_t* W2f  = (ushort_t*)(ws + F_W2F);
  ushort_t* APf  = (ushort_t*)(ws + F_APH);
  ushort_t* ysh  = (ushort_t*)(ws + F_YSH);
  ushort_t* Cf   = (ushort_t*)(ws + F_C);
  ushort_t* Ef   = (ushort_t*)(ws + F_E);
  ushort_t* ypall= (ushort_t*)(ws + F_YPALL);
  float* divsum = ws + F_DIVS;
  float* Lst    = ws + F_LST;
  float* entraw = ws + F_ENTR;
  float* ent    = ws + F_ENT;
  float* dep    = ws + F_DEP;
  float* Lp     = ws + F_LP;
  float* sap    = ws + F_SAP;
  float* scp    = ws + F_SCP;

  k_pre<<<6248, 256, 0, stream>>>(x, Wq, Wk, Wv, Wo, W2,
                                  xf, Wcat, Wof, W2f, Uf, divsum);
  k_cqkv<<<2952, 256, 0, stream>>>(Uf, xf, Wcat, Cf, Qf, Kf, Vbf, divsum, APf);

  k_phase1m<<<dim3(16, NH, 8), 512, 0, stream>>>(Qf, Kf, APf, Cf, Ef, Lp, sap, scp);
  k_combine<<<64, 256, 0, stream>>>(Lp, sap, scp, divsum, Lst, entraw, dep);
  k_entvp<<<264, 256, 0, stream>>>(entraw, ent, Vbf, dep, VT);
  k_phase2m<<<dim3(16, NH, 8), 512, 0, stream>>>(Ef, VT, Lst, dep, ypall, out2);
  k_ysum<<<1024, 256, 0, stream>>>(ypall, ent, dep, ysh);
  k_gemm64<4><<<dim3(1, 256), 256, 0, stream>>>(ysh, W2f, nullptr, ycf, 128, 192);
  k_gemm64<0><<<dim3(8, 32), 256, 0, stream>>>(ycf, Wof, out, nullptr, 1024, 1024);
}